// Round 1
// baseline (133.294 us; speedup 1.0000x reference)
//
#include <hip/hip_runtime.h>
#include <hip/hip_bf16.h>

// Problem constants
#define BB 32
#define LL 2048
#define DD 64
#define TT 512
#define INV2PI 0.15915494309189535f
// H=2, P=2 -> hp index = h*2+p in [0,4)

// Workspace layout (floats):
//   [0, BB*NCHUNK*PSTRIDE)          : per-(b,chunk) partials, 576 each
//   PREP0 .. +256                   : rp4[e][hp]   (float4 per e, e<64)
//   PREP0+256 .. +128               : feat2[e][2]  (w_rev, b_rev)
//   PREP0+384 .. +8                 : C1[4], C0[4]
//   AB0 .. +BB*128                  : per-b A[64], B[64]
#define NCHUNK 32
#define PSTRIDE 576
#define PREP0 (BB * NCHUNK * PSTRIDE)   // 589824
#define AB0 (PREP0 + 400)

// ---------------------------------------------------------------------------
// k_prep: ONE block. Everything that is batch-independent — q = query@qm_w+b,
// r[hp][i] = q . km_w cols, packed rp4[e] = {r[0][2e],r[1][2e],r[2][2e],
// r[3][2e]}, prescaled sin params (revolutions), and the closed-form linear
// coefficients C1/C0. Previously all 512 attn blocks recomputed this (the
// dominant non-memory cost of k_attn). ~2 us once instead of 512x.
// ---------------------------------------------------------------------------
__global__ void __launch_bounds__(256) k_prep(
    const float* __restrict__ te_w,
    const float* __restrict__ te_b,
    const float* __restrict__ query,
    const float* __restrict__ qm_w,
    const float* __restrict__ qm_b,
    const float* __restrict__ km_w,
    const float* __restrict__ km_b,
    float* __restrict__ ws) {
  __shared__ float q_lds[256];
  __shared__ float r_lds[512];
  const int t = threadIdx.x;
  float* prep = ws + PREP0;

  {  // q[p][e] (t = p*128+e), 4 independent accumulators
    const int p = t >> 7, e = t & 127;
    const float* qq = query + p * 128;
    const float* qw = qm_w + e;
    float a0 = 0.f, a1 = 0.f, a2 = 0.f, a3 = 0.f;
    for (int i = 0; i < 128; i += 4) {
      a0 += qq[i]     * qw[i * 128];
      a1 += qq[i + 1] * qw[(i + 1) * 128];
      a2 += qq[i + 2] * qw[(i + 2) * 128];
      a3 += qq[i + 3] * qw[(i + 3) * 128];
    }
    q_lds[t] = (a0 + a1) + (a2 + a3) + qm_b[e];
  }
  __syncthreads();

  for (int o = t; o < 512; o += 256) {  // r[hp][i]
    const int hp = o >> 7, i = o & 127;
    const int h = hp >> 1, p = hp & 1;
    const float4* km4 = (const float4*)(km_w + i * 128 + h * 64);
    const float* qp = &q_lds[p * 128 + h * 64];
    float acc = 0.f;
#pragma unroll
    for (int e4 = 0; e4 < 16; ++e4) {
      const float4 w = km4[e4];
      acc += qp[4 * e4] * w.x + qp[4 * e4 + 1] * w.y +
             qp[4 * e4 + 2] * w.z + qp[4 * e4 + 3] * w.w;
    }
    r_lds[o] = acc;
  }
  __syncthreads();

  if (t < 64) {  // pack even-index r + prescaled sin params
    float4 v;
    v.x = r_lds[0 * 128 + 2 * t];
    v.y = r_lds[1 * 128 + 2 * t];
    v.z = r_lds[2 * 128 + 2 * t];
    v.w = r_lds[3 * 128 + 2 * t];
    ((float4*)prep)[t] = v;
    prep[256 + 2 * t]     = te_w[2 * t] * INV2PI;
    prep[256 + 2 * t + 1] = te_b[2 * t] * INV2PI;
  }

  {  // C1/C0: one wave per hp, lane-parallel dot products + shfl reduce
    const int hp = t >> 6, e = t & 63;
    const int h = hp >> 1, p = hp & 1;
    const float rodd = r_lds[hp * 128 + 2 * e + 1];
    float pc1 = te_w[2 * e + 1] * rodd;
    float pc0 = te_b[2 * e + 1] * rodd +
                q_lds[p * 128 + h * 64 + e] * km_b[h * 64 + e];
#pragma unroll
    for (int off = 1; off < 64; off <<= 1) {
      pc1 += __shfl_xor(pc1, off);
      pc0 += __shfl_xor(pc0, off);
    }
    if (e == 0) {
      prep[384 + hp] = pc1;   // C1
      prep[388 + hp] = pc0;   // C0
    }
  }
}

// ---------------------------------------------------------------------------
// k_attn: grid (NCHUNK=32, BB=32) = 1024 blocks (4 blocks/CU, 16 waves/CU),
// 64 l's per block. Loads 1.6 KB of precomputed data, then:
//   scores: 4 threads/l x 16 sin-terms, shuffle-reduce within the 4-lane
//           group (no LDS round trip), exp -> w_lds
//   accumulate: masked weighted sums of X/M (the only HBM-heavy phase),
//   LDS reduce -> partial slot.
// 3 barriers total (was 7 + redundant q/r compute).
// ---------------------------------------------------------------------------
__global__ void __launch_bounds__(256) k_attn(
    const float* __restrict__ ts,
    const float* __restrict__ X,
    const float* __restrict__ M,
    float* __restrict__ ws) {
  __shared__ __align__(16) float rp4l[256];  // [e][hp]
  __shared__ __align__(8)  float f2l[128];   // [e][2] = (w_rev, b_rev)
  __shared__ float Cl[8];                    // C1[4], C0[4]
  __shared__ float tsl[64];
  __shared__ __align__(16) float w_lds[256]; // [l][hp]
  __shared__ float red[256 * 18];
  const int t = threadIdx.x;
  const int b = blockIdx.y;
  const int lc = blockIdx.x * 64;
  const float* prep = ws + PREP0;

  if (t < 64)       ((float4*)rp4l)[t] = ((const float4*)prep)[t];
  else if (t < 128) ((float2*)f2l)[t - 64] = ((const float2*)(prep + 256))[t - 64];
  else if (t < 136) Cl[t - 128] = prep[384 + (t - 128)];
  if (t >= 192) tsl[t - 192] = ts[(size_t)b * LL + lc + (t - 192)];
  __syncthreads();

  {  // scores: l = t>>2, quarter qq handles 16 of the 64 even sin terms
    const int l = t >> 2, qq = t & 3;
    const float tt = tsl[l];
    const float2* f2 = (const float2*)f2l;
    const float4* r4 = (const float4*)rp4l;
    float s0 = 0.f, s1 = 0.f, s2 = 0.f, s3 = 0.f;
#pragma unroll
    for (int i = 0; i < 16; ++i) {
      const int e = qq * 16 + i;
      const float2 wb = f2[e];
      const float f = __builtin_amdgcn_sinf(tt * wb.x + wb.y);  // sin(t*w+b)
      const float4 r = r4[e];
      s0 += f * r.x; s1 += f * r.y; s2 += f * r.z; s3 += f * r.w;
    }
    // butterfly over the 4-lane group
    s0 += __shfl_xor(s0, 1); s1 += __shfl_xor(s1, 1);
    s2 += __shfl_xor(s2, 1); s3 += __shfl_xor(s3, 1);
    s0 += __shfl_xor(s0, 2); s1 += __shfl_xor(s1, 2);
    s2 += __shfl_xor(s2, 2); s3 += __shfl_xor(s3, 2);
    // lane qq finalizes hp = qq (scores O(0.3): softmax shift-invariant, no
    // max-subtraction needed — matches reference)
    const float sv = (qq == 0) ? s0 : (qq == 1) ? s1 : (qq == 2) ? s2 : s3;
    const float w = __expf((sv + tt * Cl[qq] + Cl[4 + qq]) * 0.125f);
    w_lds[l * 4 + qq] = w;
  }
  __syncthreads();

  // accumulate: dpair in [0,32), lr row-group of 8 -> 8 rows per thread
  const int dpair = t & 31, lr = t >> 5;
  const float2* X2 = (const float2*)X;
  const float2* M2 = (const float2*)M;
  const size_t base = ((size_t)b * LL + lc) * 32;  // float2 units per row
  float n[4][2] = {}, dn[4][2] = {}, sx[2] = {};
#pragma unroll
  for (int i = 0; i < 8; ++i) {
    const int ll = lr + i * 8;
    const float2 xv = X2[base + (size_t)ll * 32 + dpair];
    const float2 mv = M2[base + (size_t)ll * 32 + dpair];
    const float mx0 = mv.x * xv.x, mx1 = mv.y * xv.y;
    sx[0] += xv.x; sx[1] += xv.y;
    const float4 wv = ((const float4*)w_lds)[ll];  // broadcast read
    n[0][0] += wv.x * mx0; n[0][1] += wv.x * mx1;
    n[1][0] += wv.y * mx0; n[1][1] += wv.y * mx1;
    n[2][0] += wv.z * mx0; n[2][1] += wv.z * mx1;
    n[3][0] += wv.w * mx0; n[3][1] += wv.w * mx1;
    dn[0][0] += wv.x * mv.x; dn[0][1] += wv.x * mv.y;
    dn[1][0] += wv.y * mv.x; dn[1][1] += wv.y * mv.y;
    dn[2][0] += wv.z * mv.x; dn[2][1] += wv.z * mv.y;
    dn[3][0] += wv.w * mv.x; dn[3][1] += wv.w * mv.y;
  }

#pragma unroll
  for (int hp = 0; hp < 4; ++hp) {
    red[t * 18 + hp * 2 + 0] = n[hp][0];
    red[t * 18 + hp * 2 + 1] = n[hp][1];
    red[t * 18 + 8 + hp * 2 + 0] = dn[hp][0];
    red[t * 18 + 8 + hp * 2 + 1] = dn[hp][1];
  }
  red[t * 18 + 16] = sx[0];
  red[t * 18 + 17] = sx[1];
  __syncthreads();

  if (t < 32) {
    float* slot = ws + ((size_t)b * NCHUNK + blockIdx.x) * PSTRIDE;
    for (int j = 0; j < 18; ++j) {
      float s = 0.f;
#pragma unroll
      for (int r2 = 0; r2 < 8; ++r2) s += red[(r2 * 32 + t) * 18 + j];
      if (j < 8) {
        const int hp = j >> 1, half = j & 1;
        slot[hp * 64 + 2 * t + half] = s;
      } else if (j < 16) {
        const int j2 = j - 8, hp = j2 >> 1, half = j2 & 1;
        slot[256 + hp * 64 + 2 * t + half] = s;
      } else {
        slot[512 + 2 * t + (j - 16)] = s;
      }
    }
  }
}

// ---------------------------------------------------------------------------
// k_coef: one block per b. Reduce 32 chunk partials -> x -> coeffs (written
// to the fp32 coeffs output) -> A,B = dec layer-1 applied to the two coeff
// rows, written to ws for k_dec.
// ---------------------------------------------------------------------------
__global__ void __launch_bounds__(256) k_coef(
    const float* __restrict__ out_w,
    const float* __restrict__ out_b,
    const float* __restrict__ dec_w1,
    const float* __restrict__ dec_b1,
    float* __restrict__ ws,
    float* __restrict__ out) {
  __shared__ __align__(16) float acc_l[576];
  __shared__ float x_lds[512];   // [p][h*128 + dd]
  __shared__ float cred[256];
  __shared__ float c_lds[128];   // coeffs [p][j]
  __shared__ float abred[256];
  const int t = threadIdx.x;
  const int b = blockIdx.x;

  if (t < 144) {  // reduce 32 chunk partials, float4-wide (576 = 144*4)
    const float4* p4 = (const float4*)(ws + (size_t)b * NCHUNK * PSTRIDE);
    float4 s; s.x = s.y = s.z = s.w = 0.f;
    for (int c = 0; c < NCHUNK; ++c) {
      const float4 v = p4[(size_t)c * 144 + t];
      s.x += v.x; s.y += v.y; s.z += v.z; s.w += v.w;
    }
    ((float4*)acc_l)[t] = s;
  }
  __syncthreads();

  {  // finalize x (t = hp*64+d); second half of value == mask -> x==1
    const int hp = t >> 6, d = t & 63;
    const int h = hp >> 1, p = hp & 1;
    const float num = acc_l[hp * 64 + d];
    const float den = acc_l[256 + hp * 64 + d];
    const float sxv = acc_l[512 + d];
    float x1, x2;
    if (den > 0.f) { x1 = num / den; x2 = 1.f; }
    else           { x1 = sxv * (1.f / (float)LL); x2 = 0.f; }  // uniform fallback
    x_lds[p * 256 + h * 128 + d] = x1;
    x_lds[p * 256 + h * 128 + 64 + d] = x2;
  }
  __syncthreads();

  {  // coeffs split-k: t = kh*128 + p*64 + j
    const int kh = t >> 7, pj = t & 127, p = pj >> 6, j = pj & 63;
    float acc = (kh == 0) ? out_b[j] : 0.f;
    const float* xp = &x_lds[p * 256 + kh * 128];
    const float* wp = out_w + (size_t)kh * 128 * 64 + j;
    for (int k = 0; k < 128; ++k) acc += xp[k] * wp[k * 64];
    cred[t] = acc;
  }
  __syncthreads();
  if (t < 128) {
    const float c = cred[t] + cred[t + 128];
    c_lds[t] = c;
    out[(size_t)BB * TT * DD + b * 128 + t] = c;  // fp32 coeffs output
  }
  __syncthreads();
  if (t < 128) {  // A,B split-j: t = jh*64 + k
    const int jh = t >> 6, k = t & 63;
    float a = 0.f, bb = 0.f;
    const float* cp = &c_lds[jh * 32];
    const float* cp2 = &c_lds[64 + jh * 32];
    for (int j = 0; j < 32; ++j) {
      const float w1 = dec_w1[(jh * 32 + j) * 64 + k];
      a += cp[j] * w1;
      bb += cp2[j] * w1;
    }
    abred[t * 2] = a;
    abred[t * 2 + 1] = bb;
  }
  __syncthreads();
  if (t < 64) {
    ws[AB0 + b * 128 + t]      = dec_b1[t] + abred[t * 2] + abred[(64 + t) * 2];
    ws[AB0 + b * 128 + 64 + t] =             abred[t * 2 + 1] + abred[(64 + t) * 2 + 1];
  }
}

// ---------------------------------------------------------------------------
// k_dec: grid (TT/64, BB) = 256 blocks. Stage w2 (16 KB) + A,B + y + b2,
// ONE barrier, then pure compute: lane = output row (t0+lane), wave = 16-d
// slice. All w2/A/B LDS reads are wave-uniform broadcasts (conflict-free);
// h1 = relu(A + y*B) is recomputed per lane (2 VALU) instead of a second
// barriered LDS round trip. ~1024 FMA/thread, no barriers in the hot loop.
// ---------------------------------------------------------------------------
__global__ void __launch_bounds__(256) k_dec(
    const float* __restrict__ yts,
    const float* __restrict__ dec_b2,
    const float* __restrict__ dec_w2,
    const float* __restrict__ ws,
    float* __restrict__ out) {
  __shared__ __align__(16) float w2l[4096];
  __shared__ float ABl[128];     // A[k] 0..63, B[k] 64..127
  __shared__ float yl[64];
  __shared__ __align__(16) float b2l[64];
  const int t = threadIdx.x;
  const int b = blockIdx.y;
  const int t0 = blockIdx.x * 64;

  {  // stage dec_w2 (16 KB) via float4
    const float4* s4 = (const float4*)dec_w2;
    float4* d4 = (float4*)w2l;
    for (int i = t; i < 1024; i += 256) d4[i] = s4[i];
  }
  if (t < 128)      ABl[t] = ws[AB0 + b * 128 + t];
  else if (t < 192) yl[t - 128] = yts[b * TT + t0 + (t - 128)];
  else              b2l[t - 192] = dec_b2[t - 192];
  __syncthreads();

  const int lane = t & 63, wv = t >> 6;  // row = t0+lane, d-slice = wv*16
  const float y = yl[lane];
  const float4* w24 = (const float4*)w2l;
  float4 acc[4];
#pragma unroll
  for (int j = 0; j < 4; ++j) acc[j] = ((const float4*)b2l)[wv * 4 + j];
  for (int k = 0; k < 64; ++k) {
    const float h = fmaxf(ABl[k] + y * ABl[64 + k], 0.f);
#pragma unroll
    for (int j = 0; j < 4; ++j) {
      const float4 w = w24[k * 16 + wv * 4 + j];
      acc[j].x += h * w.x; acc[j].y += h * w.y;
      acc[j].z += h * w.z; acc[j].w += h * w.w;
    }
  }
  const size_t off = ((size_t)b * TT + t0 + lane) * 64 + wv * 16;
#pragma unroll
  for (int j = 0; j < 4; ++j) *(float4*)(out + off + j * 4) = acc[j];
}

// ---------------------------------------------------------------------------
extern "C" void kernel_launch(void* const* d_in, const int* in_sizes, int n_in,
                              void* d_out, int out_size, void* d_ws, size_t ws_size,
                              hipStream_t stream) {
  const float* ts     = (const float*)d_in[0];
  const float* X      = (const float*)d_in[1];
  const float* M      = (const float*)d_in[2];
  const float* yts    = (const float*)d_in[3];
  const float* te_w   = (const float*)d_in[4];
  const float* te_b   = (const float*)d_in[5];
  const float* query  = (const float*)d_in[6];
  const float* qm_w   = (const float*)d_in[7];
  const float* qm_b   = (const float*)d_in[8];
  const float* km_w   = (const float*)d_in[9];
  const float* km_b   = (const float*)d_in[10];
  const float* out_w  = (const float*)d_in[11];
  const float* out_b  = (const float*)d_in[12];
  const float* dec_w1 = (const float*)d_in[13];
  const float* dec_b1 = (const float*)d_in[14];
  const float* dec_w2 = (const float*)d_in[15];
  const float* dec_b2 = (const float*)d_in[16];
  float* ws = (float*)d_ws;
  float* out = (float*)d_out;

  k_prep<<<1, 256, 0, stream>>>(te_w, te_b, query, qm_w, qm_b, km_w, km_b, ws);
  k_attn<<<dim3(NCHUNK, BB), 256, 0, stream>>>(ts, X, M, ws);
  k_coef<<<BB, 256, 0, stream>>>(out_w, out_b, dec_w1, dec_b1, ws, out);
  k_dec<<<dim3(TT / 64, BB), 256, 0, stream>>>(yts, dec_b2, dec_w2, ws, out);
}